// Round 8
// baseline (415.482 us; speedup 1.0000x reference)
//
#include <hip/hip_runtime.h>
#include <cstdint>
#include <cstddef>

// B=16, N=512, D=768, H=8, F=96;  M = B*N = 8192; GEMM N-cols = 768(h) + 768(gate) = 1536; K = 768
typedef __attribute__((ext_vector_type(4))) float f32x4;
typedef __attribute__((ext_vector_type(8))) __bf16 bf16x8;
typedef __attribute__((ext_vector_type(8))) unsigned short u16x8;
typedef __attribute__((ext_vector_type(4))) unsigned short u16x4;

__device__ __forceinline__ unsigned short f2bf(float f){
  unsigned int u = __float_as_uint(f);
  u += 0x7fffu + ((u >> 16) & 1u);          // RNE
  return (unsigned short)(u >> 16);
}
__device__ __forceinline__ float bf2f(unsigned short u){
  return __uint_as_float(((unsigned int)u) << 16);
}
__device__ __forceinline__ float fast_tanh(float x){
  const float e = __expf(2.f * x);          // inf-safe: x>>0 -> 1-0; x<<0 -> 1-2
  return 1.f - 2.f / (e + 1.f);
}

__device__ __forceinline__ void gload_lds16(const void* g, void* l){
  __builtin_amdgcn_global_load_lds((const __attribute__((address_space(1))) void*)g,
                                   (__attribute__((address_space(3))) void*)l, 16, 0, 0);
}

__device__ __forceinline__ f32x4 mfma16(bf16x8 a, bf16x8 b, f32x4 c){
  return __builtin_amdgcn_mfma_f32_16x16x32_bf16(a, b, c, 0, 0, 0);
}

#define SBAR()  { __builtin_amdgcn_sched_barrier(0); __builtin_amdgcn_s_barrier(); __builtin_amdgcn_sched_barrier(0); }

// ---------------- merged prep: emb fp32->bf16 (0..6143) + adj bitmask (6144..6655) + Bt both layers (6656..9727) ----------------
__global__ __launch_bounds__(256) void prep_kernel(const float* __restrict__ in,
                                                   unsigned short* __restrict__ out,
                                                   const float* __restrict__ adj,
                                                   unsigned int* __restrict__ mask,
                                                   const float* __restrict__ W0,
                                                   const float* __restrict__ Hw0,
                                                   unsigned short* __restrict__ Bt0,
                                                   const float* __restrict__ W1,
                                                   const float* __restrict__ Hw1,
                                                   unsigned short* __restrict__ Bt1){
  const int bid = blockIdx.x;
  if (bid < 6144){
    int i = bid * 256 + threadIdx.x;
    f32x4 v = ((const f32x4*)in)[i];
    union { unsigned short u[4]; unsigned long long ll; } o;
    #pragma unroll
    for (int e = 0; e < 4; ++e) o.u[e] = f2bf(v[e]);
    ((unsigned long long*)out)[i] = o.ll;
  } else if (bid < 6656){
    int idx = (bid - 6144) * 256 + threadIdx.x;   // 131072 words
    const float* a = adj + (size_t)idx * 32;
    unsigned int m = 0;
    #pragma unroll
    for (int e = 0; e < 8; ++e){
      f32x4 v = *(const f32x4*)(a + e * 4);
      m |= (v[0] > 0.f ? 1u : 0u) << (e * 4);
      m |= (v[1] > 0.f ? 1u : 0u) << (e * 4 + 1);
      m |= (v[2] > 0.f ? 1u : 0u) << (e * 4 + 2);
      m |= (v[3] > 0.f ? 1u : 0u) << (e * 4 + 3);
    }
    mask[idx] = m;
  } else {
    const int rel = bid - 6656;                  // 0..3071
    const int layer = rel >= 1536;
    const int n = layer ? rel - 1536 : rel;      // 0..1535
    const float* W  = layer ? W1  : W0;
    const float* Hw = layer ? Hw1 : Hw0;
    unsigned short* Bt = layer ? Bt1 : Bt0;
    const int k4 = threadIdx.x;                  // use 0..191
    if (k4 < 192){
      float v[4];
      if (n < 768){
        int head = n / 96, f = n % 96;
        const float* base = W + (size_t)head * 768 * 96 + f;
        #pragma unroll
        for (int e = 0; e < 4; ++e) v[e] = base[(size_t)(k4 * 4 + e) * 96];
      } else {
        f32x4 t = *(const f32x4*)(Hw + (size_t)(n - 768) * 768 + k4 * 4);
        #pragma unroll
        for (int e = 0; e < 4; ++e) v[e] = t[e];
      }
      union { unsigned short u[4]; unsigned long long ll; } o;
      #pragma unroll
      for (int e = 0; e < 4; ++e) o.u[e] = f2bf(v[e]);
      ((unsigned long long*)(Bt + (size_t)n * 768))[k4] = o.ll;
    }
  }
}

// ---------------- fused GEMM: C[8192][1536] = A[8192][768] * Bt^T  (BM=128, BN=64, BK=64) ----------------
// counted-vmcnt pipeline: [vmcnt(6); bar; ds_read+MFMA kt; bar; stage(kt+2)]
__global__ __launch_bounds__(256, 3)
void gemm_kernel(const unsigned short* __restrict__ A,
                 const unsigned short* __restrict__ Bt,
                 const float* __restrict__ Hb,
                 unsigned short* __restrict__ hT,
                 unsigned short* __restrict__ glogit){
  __shared__ __align__(16) char lds[49152];   // 2 bufs * (A 16KB + B 8KB); reused as epilogue tile
  const int tid  = threadIdx.x;
  const int wid  = tid >> 6;
  const int lane = tid & 63;
  // XCD-aware remap: XCD x gets mtiles [8x,8x+8) x all 24 ntiles (A panel + Bt L2-resident)
  const int orig = blockIdx.x;                 // 0..1535
  const int wgid = (orig & 7) * 192 + (orig >> 3);
  const int mtile = wgid / 24, ntile = wgid % 24;
  const int m0 = mtile * 128, n0 = ntile * 64;
  const int wm = (wid >> 1) * 64, wn = (wid & 1) * 32;
  const int g = lane >> 4, r16 = lane & 15;

  auto stage = [&](int kt, char* base){
    #pragma unroll
    for (int c = 0; c < 4; ++c){
      const int ch = c * 256 + tid;
      const int row = ch >> 3, sp = ch & 7;
      const int cj = sp ^ (row & 7);
      gload_lds16(A + (size_t)(m0 + row) * 768 + kt * 64 + cj * 8, base + ch * 16);
    }
    #pragma unroll
    for (int c = 0; c < 2; ++c){
      const int ch = c * 256 + tid;
      const int row = ch >> 3, sp = ch & 7;
      const int cj = sp ^ (row & 7);
      gload_lds16(Bt + (size_t)(n0 + row) * 768 + kt * 64 + cj * 8, base + 16384 + ch * 16);
    }
  };

  f32x4 acc[4][2];
  #pragma unroll
  for (int i = 0; i < 4; ++i)
    #pragma unroll
    for (int j = 0; j < 2; ++j) acc[i][j] = (f32x4){0.f, 0.f, 0.f, 0.f};

  stage(0, lds);
  stage(1, lds + 24576);

  for (int kt = 0; kt < 12; ++kt){
    if (kt < 11) { asm volatile("s_waitcnt vmcnt(6)" ::: "memory"); }
    else         { asm volatile("s_waitcnt vmcnt(0)" ::: "memory"); }
    SBAR();
    const char* base = lds + (kt & 1) * 24576;
    bf16x8 af[4][2], bfr[2][2];
    #pragma unroll
    for (int t = 0; t < 4; ++t){
      const int rowA = wm + t * 16 + r16;
      #pragma unroll
      for (int kk = 0; kk < 2; ++kk){
        const int ckk = (kk << 2) | g;
        af[t][kk] = *(const bf16x8*)(base + rowA * 128 + ((ckk ^ (rowA & 7)) << 4));
      }
    }
    #pragma unroll
    for (int nt = 0; nt < 2; ++nt){
      const int rowB = wn + nt * 16 + r16;
      #pragma unroll
      for (int kk = 0; kk < 2; ++kk){
        const int ckk = (kk << 2) | g;
        bfr[nt][kk] = *(const bf16x8*)(base + 16384 + rowB * 128 + ((ckk ^ (rowB & 7)) << 4));
      }
    }
    __builtin_amdgcn_s_setprio(1);
    #pragma unroll
    for (int mt = 0; mt < 4; ++mt)
      #pragma unroll
      for (int nt = 0; nt < 2; ++nt){
        acc[mt][nt] = mfma16(af[mt][0], bfr[nt][0], acc[mt][nt]);
        acc[mt][nt] = mfma16(af[mt][1], bfr[nt][1], acc[mt][nt]);
      }
    __builtin_amdgcn_s_setprio(0);
    SBAR();
    if (kt < 10) stage(kt + 2, lds + (kt & 1) * 24576);
  }

  if (n0 < 768){
    // ---- h-tile: transpose through LDS [64 n][128 m] bf16 (16KB), chunk-swizzled ----
    #pragma unroll
    for (int mt = 0; mt < 4; ++mt){
      #pragma unroll
      for (int nt = 0; nt < 2; ++nt){
        const int n_local = wn + nt * 16 + r16;
        const int m_base  = wm + mt * 16 + g * 4;
        union { unsigned short u[4]; unsigned long long ll; } pk;
        #pragma unroll
        for (int r = 0; r < 4; ++r) pk.u[r] = f2bf(acc[mt][nt][r]);
        const int byte = m_base * 2;
        const int chunk = byte >> 4, o = byte & 15;
        const int pbyte = n_local * 256 + ((chunk ^ (n_local & 15)) << 4) + o;
        *(unsigned long long*)(lds + pbyte) = pk.ll;
      }
    }
    __syncthreads();
    const int b_ = m0 >> 9, nodebase = m0 & 511;
    #pragma unroll
    for (int it = 0; it < 4; ++it){
      const int ci = it * 256 + tid;              // 0..1023
      const int row = ci >> 4, l = ci & 15;
      const int pbyte = row * 256 + (((l ^ (row & 15))) << 4);
      f32x4 v = *(const f32x4*)(lds + pbyte);
      const int n = n0 + row, head = n / 96, f = n % 96;
      *(f32x4*)(hT + (((size_t)(b_ * 8 + head)) * 96 + f) * 512 + nodebase + l * 8) = v;
    }
  } else {
    // ---- g-tile: direct-layout LDS [128 m][64 n] bf16 (16KB), chunk-swizzled ----
    #pragma unroll
    for (int mt = 0; mt < 4; ++mt){
      #pragma unroll
      for (int nt = 0; nt < 2; ++nt){
        const int n_local = wn + nt * 16 + r16;
        const float hbv = Hb[n0 - 768 + n_local];   // pre-add gate bias (fp32, before bf16 round)
        const int c = n_local >> 3;
        #pragma unroll
        for (int r = 0; r < 4; ++r){
          const int m_local = wm + mt * 16 + g * 4 + r;
          const int pbyte = m_local * 128 + ((c ^ (m_local & 7)) << 4) + (n_local & 7) * 2;
          *(unsigned short*)(lds + pbyte) = f2bf(acc[mt][nt][r] + hbv);
        }
      }
    }
    __syncthreads();
    const int colbase = n0 - 768;
    #pragma unroll
    for (int it = 0; it < 4; ++it){
      const int ci = it * 256 + tid;              // 0..1023
      const int row = ci >> 3, l = ci & 7;
      const int pbyte = row * 128 + ((l ^ (row & 7)) << 4);
      f32x4 v = *(const f32x4*)(lds + pbyte);
      *(f32x4*)(glogit + (size_t)(m0 + row) * 768 + colbase + l * 8) = v;
    }
  }
}

// ---------------- s/d projections from hT (node-contiguous, coalesced) ----------------
__global__ __launch_bounds__(256)
void sd_kernel(const unsigned short* __restrict__ hT, const float* __restrict__ asrc,
               const float* __restrict__ adst, float* __restrict__ s, float* __restrict__ d){
  const int bh = blockIdx.x;          // 0..127
  const int tid = threadIdx.x;
  const int head = bh & 7;
  __shared__ float as_lds[96], ad_lds[96];
  if (tid < 96) as_lds[tid] = asrc[head * 96 + tid];
  else if (tid >= 128 && tid < 224) ad_lds[tid - 128] = adst[head * 96 + tid - 128];
  __syncthreads();

  const unsigned short* hTb = hT + (size_t)bh * 96 * 512 + tid * 2;
  float s0 = 0.f, s1 = 0.f, d0 = 0.f, d1 = 0.f;
  #pragma unroll 8
  for (int f = 0; f < 96; ++f){
    const unsigned int u = *(const unsigned int*)(hTb + (size_t)f * 512);
    const float t0 = fast_tanh(bf2f((unsigned short)(u & 0xffffu)));
    const float t1 = fast_tanh(bf2f((unsigned short)(u >> 16)));
    const float a = as_lds[f], dd = ad_lds[f];
    s0 += t0 * a;  s1 += t1 * a;
    d0 += t0 * dd; d1 += t1 * dd;
  }
  const int o = (bh << 9) + tid * 2;
  *(float2*)(s + o) = make_float2(s0, s1);
  *(float2*)(d + o) = make_float2(d0, d1);
}

// ---------------- fused attention + softmax-PV + gate/ELU/residual/scramble ----------------
// barrier-free main loop: 4 waves = 2(i-split) x 2(j-split); V read direct from L2;
// j-reduction via LDS at the end; then coalesced combine epilogue.
__global__ __launch_bounds__(256, 4)
void attn_kernel(const float* __restrict__ s, const float* __restrict__ d,
                 const unsigned int* __restrict__ mask,     // [B][512][16]
                 const unsigned short* __restrict__ hT,     // [BH][F][N] bf16
                 const float* __restrict__ bias,            // [F]
                 const unsigned short* __restrict__ glogit, // [8192][768] bf16 (Hb pre-added)
                 const float* __restrict__ xin,             // [8192][768] fp32 residual
                 float* __restrict__ outf,                  // [8192][768] fp32
                 unsigned short* __restrict__ outb,         // bf16 copy (next-layer A)
                 int write_b){
  const int idx = blockIdx.x;           // bh = idx&127: same-bh blocks land on one XCD (128%8==0)
  const int bh = idx & 127, ib = idx >> 7;
  const int b  = bh >> 3;
  const int tid = threadIdx.x, wid = tid >> 6, lane = tid & 63;
  const int wi = wid >> 1, wj = wid & 1;      // i-split (32 rows) x j-split (256 j)
  const int g = lane >> 4, r16 = lane & 15;

  __shared__ __align__(16) char smem[25600];  // red[2][32][100] f32 ; reused as att_s [8][768] f32
  __shared__ float d_lds[512];
  __shared__ float bias_lds[96];
  __shared__ float Lred[2][2][16];
  float* red   = (float*)smem;
  float* att_s = (float*)smem;

  const float* dv = d + bh * 512;
  if (tid < 128) ((f32x4*)d_lds)[tid] = ((const f32x4*)dv)[tid];
  if (tid >= 128 && tid < 152) ((f32x4*)bias_lds)[tid - 128] = ((const f32x4*)bias)[tid - 128];

  const unsigned short* hTb = hT + (size_t)bh * 96 * 512;

  // per-lane rows: rg=0,1 -> node = ib*64 + wi*32 + rg*16 + r16
  const int row0 = ib * 64 + wi * 32;
  float s_i[2];
  s_i[0] = s[bh * 512 + row0 + r16];
  s_i[1] = s[bh * 512 + row0 + 16 + r16];

  // masks: per rg, 8 words covering this wave's 256-j window
  unsigned int mw[2][8];
  #pragma unroll
  for (int rg = 0; rg < 2; ++rg){
    const uint4* mrow = (const uint4*)(mask + ((size_t)b * 512 + row0 + rg * 16 + r16) * 16 + wj * 8);
    uint4 a0 = mrow[0], a1 = mrow[1];
    mw[rg][0]=a0.x; mw[rg][1]=a0.y; mw[rg][2]=a0.z; mw[rg][3]=a0.w;
    mw[rg][4]=a1.x; mw[rg][5]=a1.y; mw[rg][6]=a1.z; mw[rg][7]=a1.w;
  }

  __syncthreads();   // d_lds / bias ready

  // per-bh UNMASKED max of d: valid upper bound since lrelu is monotone
  float Mx = d_lds[lane];
  #pragma unroll
  for (int t = 1; t < 8; ++t) Mx = fmaxf(Mx, d_lds[t * 64 + lane]);
  #pragma unroll
  for (int o = 32; o > 0; o >>= 1) Mx = fmaxf(Mx, __shfl_xor(Mx, o));
  float m_i[2];
  #pragma unroll
  for (int rg = 0; rg < 2; ++rg){
    const float scm = s_i[rg] + Mx;
    m_i[rg] = fmaxf(scm, 0.2f * scm);
  }

  f32x4 acc[2][6];
  #pragma unroll
  for (int rg = 0; rg < 2; ++rg)
    #pragma unroll
    for (int ft = 0; ft < 6; ++ft) acc[rg][ft] = (f32x4){0.f, 0.f, 0.f, 0.f};
  float L[2] = {0.f, 0.f};

  // -------- barrier-free j sweep: 8 jt of 32 j each within this wave's 256-j strip --------
  #pragma unroll
  for (int jt = 0; jt < 8; ++jt){
    const int j8 = wj * 256 + jt * 32 + g * 8;
    // V fragments straight from global (L2-hot): 16 rows x 64B = whole cachelines
    bf16x8 vf[6];
    #pragma unroll
    for (int ft = 0; ft < 6; ++ft)
      vf[ft] = *(const bf16x8*)(hTb + (size_t)(ft * 16 + r16) * 512 + j8);

    f32x4 dA = *(const f32x4*)(d_lds + j8);
    f32x4 dB = *(const f32x4*)(d_lds + j8 + 4);
    #pragma unroll
    for (int rg = 0; rg < 2; ++rg){
      const unsigned int w = mw[rg][jt];
      u16x8 pa;
      #pragma unroll
      for (int e = 0; e < 4; ++e){
        float sc = s_i[rg] + dA[e]; sc = fmaxf(sc, 0.2f * sc);
        float p1 = ((w >> (g * 8 + e)) & 1u) ? __expf(sc - m_i[rg]) : 0.f;
        float sc2 = s_i[rg] + dB[e]; sc2 = fmaxf(sc2, 0.2f * sc2);
        float p2 = ((w >> (g * 8 + 4 + e)) & 1u) ? __expf(sc2 - m_i[rg]) : 0.f;
        L[rg] += p1; L[rg] += p2;
        pa[e] = f2bf(p1);
        pa[4 + e] = f2bf(p2);
      }
      const bf16x8 af = __builtin_bit_cast(bf16x8, pa);
      __builtin_amdgcn_s_setprio(1);
      #pragma unroll
      for (int ft = 0; ft < 6; ++ft)
        acc[rg][ft] = mfma16(af, vf[ft], acc[rg][ft]);
      __builtin_amdgcn_s_setprio(0);
    }
  }

  // wave-local L reduce over the 4 k-groups
  #pragma unroll
  for (int rg = 0; rg < 2; ++rg){
    L[rg] += __shfl_xor(L[rg], 16);
    L[rg] += __shfl_xor(L[rg], 32);
  }

  // -------- cross-wave j-reduction (wj=1 -> LDS, wj=0 adds) --------
  if (wj == 1){
    #pragma unroll
    for (int rg = 0; rg < 2; ++rg){
      #pragma unroll
      for (int ft = 0; ft < 6; ++ft)
        #pragma unroll
        for (int r = 0; r < 4; ++r)
          red[(size_t)wi * 3200 + (rg * 16 + g * 4 + r) * 100 + ft * 16 + r16] = acc[rg][ft][r];
    }
    if (lane < 16){ Lred[wi][0][lane] = L[0]; Lred[wi][1][lane] = L[1]; }
  }
  __syncthreads();
  if (wj == 0){
    #pragma unroll
    for (int rg = 0; rg < 2; ++rg){
      #pragma unroll
      for (int ft = 0; ft < 6; ++ft)
        #pragma unroll
        for (int r = 0; r < 4; ++r)
          acc[rg][ft][r] += red[(size_t)wi * 3200 + (rg * 16 + g * 4 + r) * 100 + ft * 16 + r16];
    }
    L[0] += Lred[wi][0][r16];
    L[1] += Lred[wi][1][r16];
  }
  __syncthreads();   // red reads done; region reusable as att_s

  if (wj == 0){
    float lr[2][4];
    #pragma unroll
    for (int rg = 0; rg < 2; ++rg){
      const float linv = 1.f / L[rg];
      #pragma unroll
      for (int r = 0; r < 4; ++r) lr[rg][r] = __shfl(linv, g * 4 + r);
    }
    // scatter normalized attn (+bias) into LDS out-tile [8][768]
    #pragma unroll
    for (int rg = 0; rg < 2; ++rg){
      #pragma unroll
      for (int ft = 0; ft < 6; ++ft){
        const int f = ft * 16 + r16;
        const float bv = bias_lds[f];
        #pragma unroll
        for (int r = 0; r < 4; ++r){
          const int node = row0 + rg * 16 + g * 4 + r;
          att_s[((node >> 3) & 7) * 768 + (node & 7) * 96 + f] = acc[rg][ft][r] * lr[rg][r] + bv;
        }
      }
    }
  }
  __syncthreads();

  // -------- coalesced fused gate/ELU/residual over the contiguous 8-row global range --------
  const int hh = bh & 7;
  const int bb2 = (hh << 1) | (b >> 3);
  const int mbase = bb2 * 512 + ((b & 7) << 6) + ib * 8;
  const size_t gb4 = (size_t)mbase * 192;     // f32x4 index: mbase*768/4
  #pragma unroll
  for (int sgi = 0; sgi < 6; ++sgi){
    const int ei = sgi * 256 + tid;
    f32x4 a4 = ((const f32x4*)att_s)[ei];
    u16x4 gl = ((const u16x4*)glogit)[gb4 + ei];
    f32x4 xv = ((const f32x4*)xin)[gb4 + ei];
    f32x4 o;
    #pragma unroll
    for (int e = 0; e < 4; ++e){
      const float gate = 1.f / (1.f + __expf(-bf2f(gl[e])));
      const float a = a4[e];
      const float eluv = a > 0.f ? a : (__expf(a) - 1.f);
      o[e] = gate * eluv + (1.f - gate) * xv[e];
    }
    ((f32x4*)outf)[gb4 + ei] = o;
    if (write_b){
      union { unsigned short u[4]; unsigned long long ll; } ob;
      #pragma unroll
      for (int e = 0; e < 4; ++e) ob.u[e] = f2bf(o[e]);
      ((unsigned long long*)outb)[gb4 + ei] = ob.ll;
    }
  }
}

extern "C" void kernel_launch(void* const* d_in, const int* in_sizes, int n_in,
                              void* d_out, int out_size, void* d_ws, size_t ws_size,
                              hipStream_t stream){
  const float* emb   = (const float*)d_in[0];
  const float* adj   = (const float*)d_in[1];
  const float* W0    = (const float*)d_in[3];
  const float* b0    = (const float*)d_in[4];
  const float* asrc0 = (const float*)d_in[5];
  const float* adst0 = (const float*)d_in[6];
  const float* Hw0   = (const float*)d_in[7];
  const float* Hb0   = (const float*)d_in[8];
  const float* W1    = (const float*)d_in[9];
  const float* b1    = (const float*)d_in[10];
  const float* asrc1 = (const float*)d_in[11];
  const float* adst1 = (const float*)d_in[12];
  const float* Hw1   = (const float*)d_in[13];
  const float* Hb1   = (const float*)d_in[14];

  char* ws = (char*)d_ws;
  size_t off = 0;
  auto alloc = [&](size_t bytes){ void* p = ws + off; off += (bytes + 255) & ~(size_t)255; return p; };
  unsigned short* x0b  = (unsigned short*)alloc(8192ull * 768 * 2);  // layer A input (bf16), rewritten by attn L1
  unsigned short* Bt0  = (unsigned short*)alloc(1536ull * 768 * 2);
  unsigned short* Bt1  = (unsigned short*)alloc(1536ull * 768 * 2);
  unsigned short* hT   = (unsigned short*)alloc(8192ull * 768 * 2);
  unsigned short* glogit = (unsigned short*)alloc(8192ull * 768 * 2);
  float* sbuf          = (float*)alloc(65536ull * 4);
  float* dbuf          = (float*)alloc(65536ull * 4);
  float* x1            = (float*)alloc(8192ull * 768 * 4);
  unsigned int* mask   = (unsigned int*)alloc(16ull * 512 * 16 * 4);
  (void)ws_size; (void)in_sizes; (void)n_in; (void)out_size;

  prep_kernel<<<9728, 256, 0, stream>>>(emb, x0b, adj, mask, W0, Hw0, Bt0, W1, Hw1, Bt1);

  // layer 1
  gemm_kernel<<<1536, 256, 0, stream>>>(x0b, Bt0, Hb0, hT, glogit);
  sd_kernel<<<128, 256, 0, stream>>>(hT, asrc0, adst0, sbuf, dbuf);
  attn_kernel<<<1024, 256, 0, stream>>>(sbuf, dbuf, mask, hT, b0, glogit, emb, x1, x0b, 1);

  // layer 2 (x0b now holds bf16 of x1)
  gemm_kernel<<<1536, 256, 0, stream>>>(x0b, Bt1, Hb1, hT, glogit);
  sd_kernel<<<128, 256, 0, stream>>>(hT, asrc1, adst1, sbuf, dbuf);
  attn_kernel<<<1024, 256, 0, stream>>>(sbuf, dbuf, mask, hT, b1, glogit, x1, (float*)d_out, x0b, 0);
}

// Round 9
// 239.877 us; speedup vs baseline: 1.7321x; 1.7321x over previous
//
#include <hip/hip_runtime.h>
#include <cstdint>
#include <cstddef>

// B=16, N=512, D=768, H=8, F=96;  M = B*N = 8192; GEMM N-cols = 768(h) + 768(gate) = 1536; K = 768
typedef __attribute__((ext_vector_type(4))) float f32x4;
typedef __attribute__((ext_vector_type(8))) __bf16 bf16x8;
typedef __attribute__((ext_vector_type(8))) unsigned short u16x8;
typedef __attribute__((ext_vector_type(4))) unsigned short u16x4;

__device__ __forceinline__ unsigned short f2bf(float f){
  unsigned int u = __float_as_uint(f);
  u += 0x7fffu + ((u >> 16) & 1u);          // RNE
  return (unsigned short)(u >> 16);
}
__device__ __forceinline__ float bf2f(unsigned short u){
  return __uint_as_float(((unsigned int)u) << 16);
}
__device__ __forceinline__ float fast_tanh(float x){
  const float e = __expf(2.f * x);          // inf-safe: x>>0 -> 1-0; x<<0 -> 1-2
  return 1.f - 2.f / (e + 1.f);
}

__device__ __forceinline__ void gload_lds16(const void* g, void* l){
  __builtin_amdgcn_global_load_lds((const __attribute__((address_space(1))) void*)g,
                                   (__attribute__((address_space(3))) void*)l, 16, 0, 0);
}

__device__ __forceinline__ f32x4 mfma16(bf16x8 a, bf16x8 b, f32x4 c){
  return __builtin_amdgcn_mfma_f32_16x16x32_bf16(a, b, c, 0, 0, 0);
}

#define SBAR()  { __builtin_amdgcn_sched_barrier(0); __builtin_amdgcn_s_barrier(); __builtin_amdgcn_sched_barrier(0); }

// ---------------- merged prep: emb fp32->bf16 (0..6143) + adj bitmask (6144..6655)
//                  + Bt both layers (6656..9727) + zero s/d bufs (9728..9983) ----------------
__global__ __launch_bounds__(256) void prep_kernel(const float* __restrict__ in,
                                                   unsigned short* __restrict__ out,
                                                   const float* __restrict__ adj,
                                                   unsigned int* __restrict__ mask,
                                                   const float* __restrict__ W0,
                                                   const float* __restrict__ Hw0,
                                                   unsigned short* __restrict__ Bt0,
                                                   const float* __restrict__ W1,
                                                   const float* __restrict__ Hw1,
                                                   unsigned short* __restrict__ Bt1,
                                                   float* __restrict__ sdzero){
  const int bid = blockIdx.x;
  if (bid < 6144){
    int i = bid * 256 + threadIdx.x;
    f32x4 v = ((const f32x4*)in)[i];
    union { unsigned short u[4]; unsigned long long ll; } o;
    #pragma unroll
    for (int e = 0; e < 4; ++e) o.u[e] = f2bf(v[e]);
    ((unsigned long long*)out)[i] = o.ll;
  } else if (bid < 6656){
    int idx = (bid - 6144) * 256 + threadIdx.x;   // 131072 words
    const float* a = adj + (size_t)idx * 32;
    unsigned int m = 0;
    #pragma unroll
    for (int e = 0; e < 8; ++e){
      f32x4 v = *(const f32x4*)(a + e * 4);
      m |= (v[0] > 0.f ? 1u : 0u) << (e * 4);
      m |= (v[1] > 0.f ? 1u : 0u) << (e * 4 + 1);
      m |= (v[2] > 0.f ? 1u : 0u) << (e * 4 + 2);
      m |= (v[3] > 0.f ? 1u : 0u) << (e * 4 + 3);
    }
    mask[idx] = m;
  } else if (bid < 9728){
    const int rel = bid - 6656;                  // 0..3071
    const int layer = rel >= 1536;
    const int n = layer ? rel - 1536 : rel;      // 0..1535
    const float* W  = layer ? W1  : W0;
    const float* Hw = layer ? Hw1 : Hw0;
    unsigned short* Bt = layer ? Bt1 : Bt0;
    const int k4 = threadIdx.x;                  // use 0..191
    if (k4 < 192){
      float v[4];
      if (n < 768){
        int head = n / 96, f = n % 96;
        const float* base = W + (size_t)head * 768 * 96 + f;
        #pragma unroll
        for (int e = 0; e < 4; ++e) v[e] = base[(size_t)(k4 * 4 + e) * 96];
      } else {
        f32x4 t = *(const f32x4*)(Hw + (size_t)(n - 768) * 768 + k4 * 4);
        #pragma unroll
        for (int e = 0; e < 4; ++e) v[e] = t[e];
      }
      union { unsigned short u[4]; unsigned long long ll; } o;
      #pragma unroll
      for (int e = 0; e < 4; ++e) o.u[e] = f2bf(v[e]);
      ((unsigned long long*)(Bt + (size_t)n * 768))[k4] = o.ll;
    }
  } else {
    // zero the 4 s/d buffers (s0,d0,s1,d1 contiguous: 262144 floats = 65536 f32x4)
    const int i = (bid - 9728) * 256 + threadIdx.x;
    ((f32x4*)sdzero)[i] = (f32x4){0.f, 0.f, 0.f, 0.f};
  }
}

// ---------------- fused GEMM: C[8192][1536] = A[8192][768] * Bt^T  (BM=128, BN=64, BK=64) ----------------
// counted-vmcnt pipeline: [vmcnt(6); bar; ds_read+MFMA kt; bar; stage(kt+2)]
// h-half epilogue: s/d partial reduction (atomicAdd) + hT transpose through LDS.
__global__ __launch_bounds__(256, 3)
void gemm_kernel(const unsigned short* __restrict__ A,
                 const unsigned short* __restrict__ Bt,
                 const float* __restrict__ Hb,
                 const float* __restrict__ asrc,   // [768] flat: asrc[head*96+f] == asrc[n]
                 const float* __restrict__ adst,
                 unsigned short* __restrict__ hT,
                 unsigned short* __restrict__ glogit,
                 float* __restrict__ sdst,         // [128][512]
                 float* __restrict__ ddst){
  __shared__ __align__(16) char lds[49152];   // 2 bufs * (A 16KB + B 8KB); reused as epilogue tile
  const int tid  = threadIdx.x;
  const int wid  = tid >> 6;
  const int lane = tid & 63;
  // XCD-aware remap: XCD x gets mtiles [8x,8x+8) x all 24 ntiles (A panel + Bt L2-resident)
  const int orig = blockIdx.x;                 // 0..1535
  const int wgid = (orig & 7) * 192 + (orig >> 3);
  const int mtile = wgid / 24, ntile = wgid % 24;
  const int m0 = mtile * 128, n0 = ntile * 64;
  const int wm = (wid >> 1) * 64, wn = (wid & 1) * 32;
  const int g = lane >> 4, r16 = lane & 15;

  auto stage = [&](int kt, char* base){
    #pragma unroll
    for (int c = 0; c < 4; ++c){
      const int ch = c * 256 + tid;
      const int row = ch >> 3, sp = ch & 7;
      const int cj = sp ^ (row & 7);
      gload_lds16(A + (size_t)(m0 + row) * 768 + kt * 64 + cj * 8, base + ch * 16);
    }
    #pragma unroll
    for (int c = 0; c < 2; ++c){
      const int ch = c * 256 + tid;
      const int row = ch >> 3, sp = ch & 7;
      const int cj = sp ^ (row & 7);
      gload_lds16(Bt + (size_t)(n0 + row) * 768 + kt * 64 + cj * 8, base + 16384 + ch * 16);
    }
  };

  f32x4 acc[4][2];
  #pragma unroll
  for (int i = 0; i < 4; ++i)
    #pragma unroll
    for (int j = 0; j < 2; ++j) acc[i][j] = (f32x4){0.f, 0.f, 0.f, 0.f};

  stage(0, lds);
  stage(1, lds + 24576);

  for (int kt = 0; kt < 12; ++kt){
    if (kt < 11) { asm volatile("s_waitcnt vmcnt(6)" ::: "memory"); }
    else         { asm volatile("s_waitcnt vmcnt(0)" ::: "memory"); }
    SBAR();
    const char* base = lds + (kt & 1) * 24576;
    bf16x8 af[4][2], bfr[2][2];
    #pragma unroll
    for (int t = 0; t < 4; ++t){
      const int rowA = wm + t * 16 + r16;
      #pragma unroll
      for (int kk = 0; kk < 2; ++kk){
        const int ckk = (kk << 2) | g;
        af[t][kk] = *(const bf16x8*)(base + rowA * 128 + ((ckk ^ (rowA & 7)) << 4));
      }
    }
    #pragma unroll
    for (int nt = 0; nt < 2; ++nt){
      const int rowB = wn + nt * 16 + r16;
      #pragma unroll
      for (int kk = 0; kk < 2; ++kk){
        const int ckk = (kk << 2) | g;
        bfr[nt][kk] = *(const bf16x8*)(base + 16384 + rowB * 128 + ((ckk ^ (rowB & 7)) << 4));
      }
    }
    __builtin_amdgcn_s_setprio(1);
    #pragma unroll
    for (int mt = 0; mt < 4; ++mt)
      #pragma unroll
      for (int nt = 0; nt < 2; ++nt){
        acc[mt][nt] = mfma16(af[mt][0], bfr[nt][0], acc[mt][nt]);
        acc[mt][nt] = mfma16(af[mt][1], bfr[nt][1], acc[mt][nt]);
      }
    __builtin_amdgcn_s_setprio(0);
    SBAR();
    if (kt < 10) stage(kt + 2, lds + (kt & 1) * 24576);
  }

  if (n0 < 768){
    // ---- s/d partials: wave's 32-col window [n0+wn, n0+wn+32) is within ONE head (32|96) ----
    const int headu = (n0 + wn) / 96;
    const int bb_ = m0 >> 9;           // 128-row tile never crosses a 512 boundary
    #pragma unroll
    for (int mt = 0; mt < 4; ++mt){
      float accs[4] = {0.f,0.f,0.f,0.f}, accd[4] = {0.f,0.f,0.f,0.f};
      #pragma unroll
      for (int nt = 0; nt < 2; ++nt){
        const int n = n0 + wn + nt * 16 + r16;
        const float av = asrc[n], adv = adst[n];
        #pragma unroll
        for (int r = 0; r < 4; ++r){
          const float t = fast_tanh(acc[mt][nt][r]);
          accs[r] += t * av; accd[r] += t * adv;
        }
      }
      #pragma unroll
      for (int r = 0; r < 4; ++r){
        float ssv = accs[r], ddv = accd[r];
        #pragma unroll
        for (int o = 8; o > 0; o >>= 1){ ssv += __shfl_xor(ssv, o); ddv += __shfl_xor(ddv, o); }
        if (r16 == 0){
          const int m = m0 + wm + mt * 16 + g * 4 + r;
          const int oix = ((bb_ * 8 + headu) << 9) + (m & 511);
          atomicAdd(sdst + oix, ssv);
          atomicAdd(ddst + oix, ddv);
        }
      }
    }
    // ---- h-tile: transpose through LDS [64 n][128 m] bf16 (16KB), chunk-swizzled ----
    #pragma unroll
    for (int mt = 0; mt < 4; ++mt){
      #pragma unroll
      for (int nt = 0; nt < 2; ++nt){
        const int n_local = wn + nt * 16 + r16;
        const int m_base  = wm + mt * 16 + g * 4;
        union { unsigned short u[4]; unsigned long long ll; } pk;
        #pragma unroll
        for (int r = 0; r < 4; ++r) pk.u[r] = f2bf(acc[mt][nt][r]);
        const int byte = m_base * 2;
        const int chunk = byte >> 4, o = byte & 15;
        const int pbyte = n_local * 256 + ((chunk ^ (n_local & 15)) << 4) + o;
        *(unsigned long long*)(lds + pbyte) = pk.ll;
      }
    }
    __syncthreads();
    const int b_ = m0 >> 9, nodebase = m0 & 511;
    #pragma unroll
    for (int it = 0; it < 4; ++it){
      const int ci = it * 256 + tid;              // 0..1023
      const int row = ci >> 4, l = ci & 15;
      const int pbyte = row * 256 + (((l ^ (row & 15))) << 4);
      f32x4 v = *(const f32x4*)(lds + pbyte);
      const int n = n0 + row, head = n / 96, f = n % 96;
      *(f32x4*)(hT + (((size_t)(b_ * 8 + head)) * 96 + f) * 512 + nodebase + l * 8) = v;
    }
  } else {
    // ---- g-tile: direct-layout LDS [128 m][64 n] bf16 (16KB), chunk-swizzled ----
    #pragma unroll
    for (int mt = 0; mt < 4; ++mt){
      #pragma unroll
      for (int nt = 0; nt < 2; ++nt){
        const int n_local = wn + nt * 16 + r16;
        const float hbv = Hb[n0 - 768 + n_local];   // pre-add gate bias (fp32, before bf16 round)
        const int c = n_local >> 3;
        #pragma unroll
        for (int r = 0; r < 4; ++r){
          const int m_local = wm + mt * 16 + g * 4 + r;
          const int pbyte = m_local * 128 + ((c ^ (m_local & 7)) << 4) + (n_local & 7) * 2;
          *(unsigned short*)(lds + pbyte) = f2bf(acc[mt][nt][r] + hbv);
        }
      }
    }
    __syncthreads();
    const int colbase = n0 - 768;
    #pragma unroll
    for (int it = 0; it < 4; ++it){
      const int ci = it * 256 + tid;              // 0..1023
      const int row = ci >> 3, l = ci & 7;
      const int pbyte = row * 128 + ((l ^ (row & 7)) << 4);
      f32x4 v = *(const f32x4*)(lds + pbyte);
      *(f32x4*)(glogit + (size_t)(m0 + row) * 768 + colbase + l * 8) = v;
    }
  }
}

// ---------------- fused attention + softmax-PV + gate/ELU/residual/scramble ----------------
// 3-buffer counted-vmcnt pipeline: [vmcnt(3); bar; stage(p+2) || compute p]
// residual flows in bf16; L1 rewrites xio in place (disjoint 8-row blocks, read-before-write)
__global__ __launch_bounds__(256)
void attn_kernel(const float* __restrict__ s, const float* __restrict__ d,
                 const unsigned int* __restrict__ mask,     // [B][512][16]
                 const unsigned short* __restrict__ hT,     // [BH][F][N] bf16
                 const float* __restrict__ bias,            // [F]
                 const unsigned short* __restrict__ glogit, // [8192][768] bf16 (Hb pre-added)
                 const unsigned short* __restrict__ xin,    // [8192][768] bf16 residual
                 float* __restrict__ outf,                  // fp32 out (layer 2 -> d_out)
                 unsigned short* __restrict__ outb,         // bf16 out (layer 1 -> next A)
                 int write_f, int write_b){
  const int idx = blockIdx.x;           // bh = idx&127 keeps same-bh blocks on one XCD
  const int bh = idx & 127, ib = idx >> 7;
  const int b  = bh >> 3;
  const int tid = threadIdx.x, wid = tid >> 6, lane = tid & 63;
  const int g = lane >> 4, r16 = lane & 15;
  const int rowbase = ib * 64 + wid * 16;

  __shared__ float d_lds[512];
  __shared__ float bias_lds[96];
  __shared__ __align__(16) char vbuf[3][12288];   // V slices; [0..1] reused as fp32 out tile [8][768]
  float* att_s = (float*)vbuf;

  const float* dv = d + bh * 512;
  if (tid < 128) ((f32x4*)d_lds)[tid] = ((const f32x4*)dv)[tid];
  if (tid >= 128 && tid < 152) ((f32x4*)bias_lds)[tid - 128] = ((const f32x4*)bias)[tid - 128];

  const unsigned short* hTb = hT + (size_t)bh * 96 * 512;

  auto stage = [&](int p, int bufi){
    #pragma unroll
    for (int ss2 = 0; ss2 < 3; ++ss2){
      const int ch = ss2 * 256 + tid;
      const int row = ch >> 3, slotpos = ch & 7;
      const int cj = slotpos ^ (row & 7);
      gload_lds16(hTb + (size_t)row * 512 + p * 64 + cj * 8, vbuf[bufi] + ch * 16);
    }
  };

  const int i_mine = rowbase + r16;     // this lane's P-row
  const float s_i = s[bh * 512 + i_mine];

  unsigned int mw[16];
  {
    const uint4* mrow = (const uint4*)(mask + ((size_t)b * 512 + i_mine) * 16);
    uint4 a0 = mrow[0], a1 = mrow[1], a2 = mrow[2], a3 = mrow[3];
    mw[0]=a0.x; mw[1]=a0.y; mw[2]=a0.z; mw[3]=a0.w;
    mw[4]=a1.x; mw[5]=a1.y; mw[6]=a1.z; mw[7]=a1.w;
    mw[8]=a2.x; mw[9]=a2.y; mw[10]=a2.z; mw[11]=a2.w;
    mw[12]=a3.x; mw[13]=a3.y; mw[14]=a3.z; mw[15]=a3.w;
  }

  stage(0, 0);
  stage(1, 1);
  asm volatile("s_waitcnt lgkmcnt(0)" ::: "memory");   // d_lds/bias ds_writes visible before first barrier

  float m_i;
  f32x4 acc2[6];
  #pragma unroll
  for (int ft = 0; ft < 6; ++ft) acc2[ft] = (f32x4){0.f, 0.f, 0.f, 0.f};
  float L0 = 0.f, L1 = 0.f, L2 = 0.f, L3 = 0.f;

  #pragma unroll
  for (int p = 0; p < 8; ++p){
    if (p < 7) { asm volatile("s_waitcnt vmcnt(3)" ::: "memory"); }
    else       { asm volatile("s_waitcnt vmcnt(0)" ::: "memory"); }
    SBAR();
    if (p == 0){
      float Mx = d_lds[lane];
      #pragma unroll
      for (int t = 1; t < 8; ++t) Mx = fmaxf(Mx, d_lds[t * 64 + lane]);
      #pragma unroll
      for (int o = 32; o > 0; o >>= 1) Mx = fmaxf(Mx, __shfl_xor(Mx, o));
      const float scm = s_i + Mx;
      m_i = fmaxf(scm, 0.2f * scm);    // lrelu monotone => valid upper bound for all rows
    }
    if (p < 6) stage(p + 2, (p + 2) % 3);
    const char* vb = vbuf[p % 3];
    #pragma unroll
    for (int half = 0; half < 2; ++half){
      const int jt = p * 2 + half;
      const unsigned int w = mw[jt];
      const int j8 = jt * 32 + g * 8;
      f32x4 dA = *(const f32x4*)(d_lds + j8);
      f32x4 dB = *(const f32x4*)(d_lds + j8 + 4);
      u16x8 pa;
      #pragma unroll
      for (int e = 0; e < 4; ++e){
        float sc = s_i + dA[e]; sc = fmaxf(sc, 0.2f * sc);
        float p1 = ((w >> (g * 8 + e)) & 1u) ? __expf(sc - m_i) : 0.f;
        float sc2 = s_i + dB[e]; sc2 = fmaxf(sc2, 0.2f * sc2);
        float p2 = ((w >> (g * 8 + 4 + e)) & 1u) ? __expf(sc2 - m_i) : 0.f;
        // 4 independent L-chains (32 deep each) instead of one 128-deep chain
        if (e == 0){ L0 += p1; L0 += p2; } else if (e == 1){ L1 += p1; L1 += p2; }
        else if (e == 2){ L2 += p1; L2 += p2; } else { L3 += p1; L3 += p2; }
        pa[e] = f2bf(p1);
        pa[4 + e] = f2bf(p2);
      }
      const bf16x8 af = __builtin_bit_cast(bf16x8, pa);
      const int slot = ((half * 4 + g) ^ (r16 & 7)) * 16;
      __builtin_amdgcn_s_setprio(1);
      #pragma unroll
      for (int ft = 0; ft < 6; ++ft){
        bf16x8 vf = *(const bf16x8*)(vb + (ft * 16 + r16) * 128 + slot);
        acc2[ft] = mfma16(af, vf, acc2[ft]);
      }
      __builtin_amdgcn_s_setprio(0);
    }
  }
  __syncthreads();   // all compute done; att_s (vbuf[0..1]) free for reuse

  float L = (L0 + L1) + (L2 + L3);
  L += __shfl_xor(L, 16);
  L += __shfl_xor(L, 32);
  const float linv = 1.f / L;
  float lr[4];
  #pragma unroll
  for (int r = 0; r < 4; ++r) lr[r] = __shfl(linv, g * 4 + r);  // linv of row rowbase+g*4+r

  // phase 1: scatter normalized attn (+bias) into LDS out-tile [8][768]
  #pragma unroll
  for (int ft = 0; ft < 6; ++ft){
    const int f = ft * 16 + r16;
    const float bv = bias_lds[f];
    #pragma unroll
    for (int r = 0; r < 4; ++r){
      const int node = rowbase + g * 4 + r;
      att_s[((node >> 3) & 7) * 768 + (node & 7) * 96 + f] = acc2[ft][r] * lr[r] + bv;
    }
  }
  __syncthreads();

  // phase 2: coalesced fused gate/ELU/residual over the contiguous 8-row global range
  const int hh = bh & 7;
  const int bb2 = (hh << 1) | (b >> 3);
  const int mbase = bb2 * 512 + ((b & 7) << 6) + ib * 8;
  const size_t gb4 = (size_t)mbase * 192;     // 4-elem group index: mbase*768/4
  #pragma unroll
  for (int sgi = 0; sgi < 6; ++sgi){
    const int ei = sgi * 256 + tid;
    f32x4 a4 = ((const f32x4*)att_s)[ei];
    u16x4 gl = ((const u16x4*)glogit)[gb4 + ei];
    u16x4 xv = ((const u16x4*)xin)[gb4 + ei];
    f32x4 o;
    #pragma unroll
    for (int e = 0; e < 4; ++e){
      const float gate = 1.f / (1.f + __expf(-bf2f(gl[e])));
      const float a = a4[e];
      const float eluv = a > 0.f ? a : (__expf(a) - 1.f);
      o[e] = gate * eluv + (1.f - gate) * bf2f(xv[e]);
    }
    if (write_f) ((f32x4*)outf)[gb4 + ei] = o;
    if (write_b){
      union { unsigned short u[4]; unsigned long long ll; } ob;
      #pragma unroll
      for (int e = 0; e < 4; ++e) ob.u[e] = f2bf(o[e]);
      ((unsigned long long*)outb)[gb4 + ei] = ob.ll;
    }
  }
}

extern "C" void kernel_launch(void* const* d_in, const int* in_sizes, int n_in,
                              void* d_out, int out_size, void* d_ws, size_t ws_size,
                              hipStream_t stream){
  const float* emb   = (const float*)d_in[0];
  const float* adj   = (const float*)d_in[1];
  const float* W0    = (const float*)d_in[3];
  const float* b0    = (const float*)d_in[4];
  const float* asrc0 = (const float*)d_in[5];
  const float* adst0 = (const float*)d_in[6];
  const float* Hw0   = (const float*)d_in[7];
  const float* Hb0   = (const float*)d_in[8];
  const float* W1    = (const float*)d_in[9];
  const float* b1    = (const float*)d_in[10];
  const float* asrc1 = (const float*)d_in[11];
  const float* adst1 = (const float*)d_in[12];
  const float* Hw1   = (const float*)d_in[13];
  const float* Hb1   = (const float*)d_in[14];

  char* ws = (char*)d_ws;
  size_t off = 0;
  auto alloc = [&](size_t bytes){ void* p = ws + off; off += (bytes + 255) & ~(size_t)255; return p; };
  unsigned short* x0b  = (unsigned short*)alloc(8192ull * 768 * 2);  // bf16 layer input/residual, rewritten in place by attn L1
  unsigned short* Bt0  = (unsigned short*)alloc(1536ull * 768 * 2);
  unsigned short* Bt1  = (unsigned short*)alloc(1536ull * 768 * 2);
  unsigned short* hT   = (unsigned short*)alloc(8192ull * 768 * 2);
  unsigned short* glogit = (unsigned short*)alloc(8192ull * 768 * 2);
  float* sd0           = (float*)alloc(2ull * 65536 * 4);   // s0 | d0
  float* sd1           = (float*)alloc(2ull * 65536 * 4);   // s1 | d1  (contiguous after sd0)
  unsigned int* mask   = (unsigned int*)alloc(16ull * 512 * 16 * 4);
  float* s0 = sd0, *d0 = sd0 + 65536;
  float* s1 = sd1, *d1 = sd1 + 65536;
  (void)ws_size; (void)in_sizes; (void)n_in; (void)out_size;

  prep_kernel<<<9984, 256, 0, stream>>>(emb, x0b, adj, mask, W0, Hw0, Bt0, W1, Hw1, Bt1, sd0);

  // layer 1
  gemm_kernel<<<1536, 256, 0, stream>>>(x0b, Bt0, Hb0, asrc0, adst0, hT, glogit, s0, d0);
  attn_kernel<<<1024, 256, 0, stream>>>(s0, d0, mask, hT, b0, glogit, x0b, (float*)d_out, x0b, 0, 1);

  // layer 2 (x0b now holds bf16 of x1)
  gemm_kernel<<<1536, 256, 0, stream>>>(x0b, Bt1, Hb1, asrc1, adst1, hT, glogit, s1, d1);
  attn_kernel<<<1024, 256, 0, stream>>>(s1, d1, mask, hT, b1, glogit, x0b, (float*)d_out, x0b, 1, 0);
}